// Round 6
// baseline (614.944 us; speedup 1.0000x reference)
//
#include <hip/hip_runtime.h>

typedef unsigned short u16;
typedef __bf16 bf16x8 __attribute__((ext_vector_type(8)));
typedef float f32x4 __attribute__((ext_vector_type(4)));
typedef u16 u16x8 __attribute__((ext_vector_type(8)));

#define M_DIM 8192
#define N_DIM 4096
#define K_DIM 4096
#define BM 256
#define BN 256
#define BK 32
#define NT (K_DIM / BK)  // 128 K-tiles

__device__ __forceinline__ u16 f2b(float f) {
  unsigned int x = __float_as_uint(f);
  unsigned int r = (x + 0x7fffu + ((x >> 16) & 1u)) >> 16;
  return (u16)r;
}

#define GLOAD_LDS16(gp, lp)                                        \
  __builtin_amdgcn_global_load_lds(                                \
      (const __attribute__((address_space(1))) void*)(gp),         \
      (__attribute__((address_space(3))) void*)(lp), 16, 0, 0)

// Counted wait (vm: oldest beyond N drain; lgkm: all ds ops done so no
// read crosses the following barrier) + rule-#18 fence.
#define WAIT8                                                      \
  do {                                                             \
    asm volatile("s_waitcnt vmcnt(8) lgkmcnt(0)" ::: "memory");    \
    __builtin_amdgcn_sched_barrier(0);                             \
  } while (0)
#define BARF                                                       \
  do {                                                             \
    __builtin_amdgcn_s_barrier();                                  \
    __builtin_amdgcn_sched_barrier(0);                             \
  } while (0)

// ---------------------------------------------------------------------------
// Kernel 0: convert x fp32 -> bf16. 8 elements / thread. (proven)
// ---------------------------------------------------------------------------
__global__ __launch_bounds__(256) void cvt_x(const float* __restrict__ X,
                                             u16* __restrict__ Xb) {
  const size_t t = (size_t)blockIdx.x * 256 + threadIdx.x;
  const f32x4* src = (const f32x4*)X + t * 2;
  f32x4 a = src[0];
  f32x4 b = src[1];
  u16x8 o;
  o[0] = f2b(a[0]); o[1] = f2b(a[1]); o[2] = f2b(a[2]); o[3] = f2b(a[3]);
  o[4] = f2b(b[0]); o[5] = f2b(b[1]); o[6] = f2b(b[2]); o[7] = f2b(b[3]);
  *((u16x8*)Xb + t) = o;
}

// ---------------------------------------------------------------------------
// Kernel 1: Weff build (proven, unchanged)
// ---------------------------------------------------------------------------
__global__ __launch_bounds__(256) void build_weff(
    const float* __restrict__ W, const float* __restrict__ Au,
    const float* __restrict__ Bu, const float* __restrict__ A0,
    const float* __restrict__ B0, u16* __restrict__ Weff) {
  __shared__ float coef[64 * 16];  // coef[r][oi]
  const int t = threadIdx.x;
  const int o0 = blockIdx.y * 16;

#pragma unroll
  for (int j = 0; j < 4; j++) {
    const int idx = t + j * 256;     // 0..1023
    const int r = idx >> 4;          // 0..63
    const int oi = idx & 15;
    const int o = o0 + oi;
    float v;
    if (r < 8) {
      v = Bu[o * 8 + r];
    } else {
      const int rs = r - 8;
      if (o < 2048) {
        v = B0[o * 56 + rs];
      } else {
        const int rr = rs ? (rs - 1) : 55;
        v = B0[(o - 2048) * 56 + rr];
      }
    }
    coef[r * 16 + oi] = v;
  }
  __syncthreads();

  const int d0 = blockIdx.x * 1024 + t * 4;
  const int hi = (d0 >= 2048);
  const int dd = hi ? (d0 - 2048) : d0;

  f32x4 acc[16] = {};

#pragma unroll
  for (int r = 0; r < 8; r++) {
    f32x4 a = *(const f32x4*)(Au + (size_t)r * 4096 + d0);
    const float* cr = &coef[r * 16];
#pragma unroll
    for (int oi = 0; oi < 16; oi++) {
      const float c = cr[oi];
      acc[oi][0] += c * a[0]; acc[oi][1] += c * a[1];
      acc[oi][2] += c * a[2]; acc[oi][3] += c * a[3];
    }
  }
#pragma unroll 4
  for (int rs = 0; rs < 56; rs++) {
    const int rr = hi ? (rs ? (rs - 1) : 55) : rs;
    f32x4 a = *(const f32x4*)(A0 + (size_t)rr * 2048 + dd);
    const float* cr = &coef[(rs + 8) * 16];
#pragma unroll
    for (int oi = 0; oi < 16; oi++) {
      const float c = cr[oi];
      acc[oi][0] += c * a[0]; acc[oi][1] += c * a[1];
      acc[oi][2] += c * a[2]; acc[oi][3] += c * a[3];
    }
  }

#pragma unroll
  for (int oi = 0; oi < 16; oi++) {
    f32x4 w = *(const f32x4*)(W + (size_t)(o0 + oi) * 4096 + d0);
    ushort4 ov;
    ov.x = f2b(acc[oi][0] + w[0]);
    ov.y = f2b(acc[oi][1] + w[1]);
    ov.z = f2b(acc[oi][2] + w[2]);
    ov.w = f2b(acc[oi][3] + w[3]);
    *(ushort4*)(Weff + (size_t)(o0 + oi) * 4096 + d0) = ov;
  }
}

// ---------------------------------------------------------------------------
// Kernel 2: C[m][n] = sum_k Xb[m][k]*Weff[n][k] + bias[n]   (bf16 MFMA, NT)
//
// AITER-shape loop in plain HIP: 256x256 tile, BK=32, FOUR LDS buffers
// (tile t -> buf t&3), ONE barrier / K-tile, ~32 MFMA per barrier,
// vmcnt never 0 in the loop, 3-tile-deep DMA prefetch.
//
// body(T): { stage tile T+3 -> buf[(T+3)&3] (4 DMA);
//            s_waitcnt vmcnt(8) lgkmcnt(0); barrier;   // tile T+1 landed
//            READ frags(T+1) from buf[(T+1)&3] (12 ds_read_b128, ping-pong);
//             32 MFMA on frags(T) (regs, no waits) }
// Ledger (per wave): 12 in flight at the wait, drains oldest 4 = tile T+1
//   (staged 2 bodies ago ~2600 cyc > 900-cyc HBM miss). Uniform incl. tail
//   (T+1/T+3 clamped to NT-1; dup stages land in rotating bufs, never read).
// Cross-wave visibility: every wave's own tile-T+1 loads drained by its
//   WAIT8 before the barrier; lgkmcnt(0) keeps ds_reads from crossing BAR.
// WAR: stage(T+3) overwrites buf[(T-1)&3]; its last reads (READ(T-1), body
//   T-2) are >=1 barrier earlier and lgkm-drained before that barrier.
// Frags read one full body before their MFMA -> no lgkm stall before MFMA.
// Swizzle (BK=32, 64-B rows): read 16B-block = quad ^ ((l16>>1)&3); inverse
//   pre-applied to the per-lane global source (linear LDS dest). Uniform
//   8 lanes per 4-bank group -> bandwidth-optimal, zero conflicts.
// ---------------------------------------------------------------------------
__global__ __launch_bounds__(512, 2) void gemm_bt_bias(
    const u16* __restrict__ X, const u16* __restrict__ Wf,
    const float* __restrict__ bias, float* __restrict__ C) {
  __shared__ __align__(16) u16 lds[65536];  // 128 KiB: A bufs [0,64K)B, B bufs [64K,128K)B

  const int tid = threadIdx.x;
  const int wave = tid >> 6;
  const int lane = tid & 63;
  const int wm = wave >> 2;    // 0..1
  const int wn = wave & 3;     // 0..3
  const int quad = lane >> 4;  // 0..3
  const int l16 = lane & 15;

  // T1: XCD-aware swizzle (512 blocks, 64 per XCD, n-fastest).
  const int wgid = ((blockIdx.x & 7) << 6) | (blockIdx.x >> 3);
  const int n0 = (wgid & 15) * BN;  // 16 n-tiles
  const int m0 = (wgid >> 4) * BM;  // 32 m-tiles

  // Staging: each SG covers 16 rows x 32 k (1 KiB): row = lane>>2, 16B-block
  // = lane&3; linear LDS dest; global source col pre-inverse-swizzled.
  const int sr = lane >> 2;                              // 0..15
  const int scol = (((lane & 3) ^ ((lane >> 3) & 3)) << 3);  // elems
  const u16* xg = X + (size_t)(m0 + wave * 32 + sr) * K_DIM + scol;
  const u16* wg = Wf + (size_t)(n0 + wave * 32 + sr) * K_DIM + scol;
  u16* lA = lds + wave * 1024;           // wave's 32 A-rows (32 u16 each)
  u16* lB = lds + 32768 + wave * 1024;

#define SG_A(b, la, kt)                                                     \
  GLOAD_LDS16(xg + (size_t)(la) * 16 * K_DIM + (size_t)(kt) * BK,           \
              lA + (b) * 8192 + (la) * 512)
#define SG_B(b, la, kt)                                                     \
  GLOAD_LDS16(wg + (size_t)(la) * 16 * K_DIM + (size_t)(kt) * BK,           \
              lB + (b) * 8192 + (la) * 512)
#define SG_TILE(b, kt)                                                      \
  do {                                                                      \
    SG_A(b, 0, kt); SG_A(b, 1, kt);                                         \
    SG_B(b, 0, kt); SG_B(b, 1, kt);                                         \
  } while (0)

  f32x4 acc[8][4] = {};
  bf16x8 a0[8], b0[4];  // frag set 0 (even tiles)
  bf16x8 a1[8], b1[4];  // frag set 1 (odd tiles)

  // Read addressing: row*64 B + swizzled 16B block; per-buf/mi/ni offsets
  // are compile-time immediates (max imm 64.5K/52K+base < 64K ds offset).
  const int swb = ((quad ^ ((l16 >> 1) & 3)) << 4);
  const int aoff = (wm * 128 + l16) * 64 + swb;          // byte, A region
  const int boff = 65536 + (wn * 64 + l16) * 64 + swb;   // byte, B region

#define READF(AF, BF, b)                                                    \
  do {                                                                      \
    const char* p_ = (const char*)lds;                                      \
    _Pragma("unroll") for (int mi = 0; mi < 8; mi++)                        \
        AF[mi] = *(const bf16x8*)(p_ + (b) * 16384 + mi * 1024 + aoff);     \
    _Pragma("unroll") for (int ni = 0; ni < 4; ni++)                        \
        BF[ni] = *(const bf16x8*)(p_ + (b) * 16384 + ni * 1024 + boff);     \
  } while (0)

#define MFMA32(AF, BF)                                                      \
  do {                                                                      \
    __builtin_amdgcn_s_setprio(1);                                          \
    _Pragma("unroll") for (int mi = 0; mi < 8; mi++) {                      \
      _Pragma("unroll") for (int ni = 0; ni < 4; ni++) {                    \
        acc[mi][ni] = __builtin_amdgcn_mfma_f32_16x16x32_bf16(              \
            AF[mi], BF[ni], acc[mi][ni], 0, 0, 0);                          \
      }                                                                     \
    }                                                                       \
    __builtin_amdgcn_s_setprio(0);                                          \
  } while (0)

#define BODY(Tc, SGB, RDB, RA, RB, MA, MB)                                  \
  do {                                                                      \
    const int kt_ = ((Tc) + 3 < NT) ? (Tc) + 3 : NT - 1;                    \
    SG_TILE(SGB, kt_);                                                      \
    WAIT8;                                                                  \
    BARF;                                                                   \
    READF(RA, RB, RDB);                                                     \
    MFMA32(MA, MB);                                                         \
  } while (0)

  // Prologue: stage tiles 0,1,2 (12 loads); drain tile 0; read its frags.
  SG_TILE(0, 0);
  SG_TILE(1, 1);
  SG_TILE(2, 2);
  WAIT8;
  BARF;
  READF(a0, b0, 0);

  for (int u = 0; u < NT / 4; ++u) {
    const int T = u * 4;
    BODY(T + 0, 3, 1, a1, b1, a0, b0);
    BODY(T + 1, 0, 2, a0, b0, a1, b1);
    BODY(T + 2, 1, 3, a1, b1, a0, b0);
    BODY(T + 3, 2, 0, a0, b0, a1, b1);
  }
  asm volatile("s_waitcnt vmcnt(0)" ::: "memory");  // drain dup DMAs

  // Epilogue: C/D layout col=l16 (B-frag j), row=quad*4+reg (A-frag i).
#pragma unroll
  for (int j = 0; j < 4; j++) {
    const int col = n0 + wn * 64 + j * 16 + l16;
    const float bv = bias[col];
#pragma unroll
    for (int i = 0; i < 8; i++) {
      const int row = m0 + wm * 128 + i * 16 + quad * 4;
#pragma unroll
      for (int r = 0; r < 4; r++) {
        C[(size_t)(row + r) * N_DIM + col] = acc[i][j][r] + bv;
      }
    }
  }
}

extern "C" void kernel_launch(void* const* d_in, const int* in_sizes, int n_in,
                              void* d_out, int out_size, void* d_ws, size_t ws_size,
                              hipStream_t stream) {
  const float* x  = (const float*)d_in[0];  // [4,2048,4096] fp32
  const float* W  = (const float*)d_in[1];  // [4096,4096] fp32
  const float* b  = (const float*)d_in[2];  // [4096] fp32
  const float* Au = (const float*)d_in[3];  // [8,4096] fp32
  const float* Bu = (const float*)d_in[4];  // [4096,8] fp32
  const float* A0 = (const float*)d_in[5];  // [56,2048] fp32
  const float* B0 = (const float*)d_in[6];  // [2048,56] fp32
  float* out = (float*)d_out;               // [4,2048,4096] fp32

  u16* Xb   = (u16*)d_ws;                                      // 64 MB
  u16* Weff = (u16*)((char*)d_ws + (size_t)64 * 1024 * 1024);  // 32 MB

  cvt_x<<<16384, 256, 0, stream>>>(x, Xb);
  build_weff<<<dim3(4, 256), 256, 0, stream>>>(W, Au, Bu, A0, B0, Weff);
  gemm_bt_bias<<<dim3(512), dim3(512), 0, stream>>>(Xb, Weff, b, out);
}

// Round 7
// 546.801 us; speedup vs baseline: 1.1246x; 1.1246x over previous
//
#include <hip/hip_runtime.h>

typedef unsigned short u16;
typedef __bf16 bf16x8 __attribute__((ext_vector_type(8)));
typedef float f32x4 __attribute__((ext_vector_type(4)));
typedef u16 u16x8 __attribute__((ext_vector_type(8)));

#define M_DIM 8192
#define N_DIM 4096
#define K_DIM 4096
#define BM 256
#define BN 256
#define BK 64
#define NT (K_DIM / BK)  // 64 K-tiles

__device__ __forceinline__ u16 f2b(float f) {
  unsigned int x = __float_as_uint(f);
  unsigned int r = (x + 0x7fffu + ((x >> 16) & 1u)) >> 16;
  return (u16)r;
}

#define GLOAD_LDS16(gp, lp)                                        \
  __builtin_amdgcn_global_load_lds(                                \
      (const __attribute__((address_space(1))) void*)(gp),         \
      (__attribute__((address_space(3))) void*)(lp), 16, 0, 0)

#define BAR __builtin_amdgcn_s_barrier()
// Counted vmem wait + rule-#18 fence (no ds_read hoisted across the wait).
#define VMW(N)                                                     \
  do {                                                             \
    asm volatile("s_waitcnt vmcnt(" #N ")" ::: "memory");          \
    __builtin_amdgcn_sched_barrier(0);                             \
  } while (0)

// T19 weave: pin emitted order to {gloads; (ds_read x k; MFMA x 4) x 4}.
// Masks (LLVM SchedGroupMask): VMEM*=0x70, DS_READ=0x100, MFMA=0x8.
#define SGB(m, n) __builtin_amdgcn_sched_group_barrier((m), (n), 0)
#define WEAVE_4R                                                   \
  do {                                                             \
    SGB(0x100, 1); SGB(0x8, 4); SGB(0x100, 1); SGB(0x8, 4);        \
    SGB(0x100, 1); SGB(0x8, 4); SGB(0x100, 1); SGB(0x8, 4);        \
  } while (0)
#define WEAVE_8R                                                   \
  do {                                                             \
    SGB(0x100, 2); SGB(0x8, 4); SGB(0x100, 2); SGB(0x8, 4);        \
    SGB(0x100, 2); SGB(0x8, 4); SGB(0x100, 2); SGB(0x8, 4);        \
  } while (0)

// ---------------------------------------------------------------------------
// Kernel 0: convert x fp32 -> bf16. 8 elements / thread. (proven)
// ---------------------------------------------------------------------------
__global__ __launch_bounds__(256) void cvt_x(const float* __restrict__ X,
                                             u16* __restrict__ Xb) {
  const size_t t = (size_t)blockIdx.x * 256 + threadIdx.x;
  const f32x4* src = (const f32x4*)X + t * 2;
  f32x4 a = src[0];
  f32x4 b = src[1];
  u16x8 o;
  o[0] = f2b(a[0]); o[1] = f2b(a[1]); o[2] = f2b(a[2]); o[3] = f2b(a[3]);
  o[4] = f2b(b[0]); o[5] = f2b(b[1]); o[6] = f2b(b[2]); o[7] = f2b(b[3]);
  *((u16x8*)Xb + t) = o;
}

// ---------------------------------------------------------------------------
// Kernel 1: Weff build (proven, unchanged)
// ---------------------------------------------------------------------------
__global__ __launch_bounds__(256) void build_weff(
    const float* __restrict__ W, const float* __restrict__ Au,
    const float* __restrict__ Bu, const float* __restrict__ A0,
    const float* __restrict__ B0, u16* __restrict__ Weff) {
  __shared__ float coef[64 * 16];  // coef[r][oi]
  const int t = threadIdx.x;
  const int o0 = blockIdx.y * 16;

#pragma unroll
  for (int j = 0; j < 4; j++) {
    const int idx = t + j * 256;     // 0..1023
    const int r = idx >> 4;          // 0..63
    const int oi = idx & 15;
    const int o = o0 + oi;
    float v;
    if (r < 8) {
      v = Bu[o * 8 + r];
    } else {
      const int rs = r - 8;
      if (o < 2048) {
        v = B0[o * 56 + rs];
      } else {
        const int rr = rs ? (rs - 1) : 55;
        v = B0[(o - 2048) * 56 + rr];
      }
    }
    coef[r * 16 + oi] = v;
  }
  __syncthreads();

  const int d0 = blockIdx.x * 1024 + t * 4;
  const int hi = (d0 >= 2048);
  const int dd = hi ? (d0 - 2048) : d0;

  f32x4 acc[16] = {};

#pragma unroll
  for (int r = 0; r < 8; r++) {
    f32x4 a = *(const f32x4*)(Au + (size_t)r * 4096 + d0);
    const float* cr = &coef[r * 16];
#pragma unroll
    for (int oi = 0; oi < 16; oi++) {
      const float c = cr[oi];
      acc[oi][0] += c * a[0]; acc[oi][1] += c * a[1];
      acc[oi][2] += c * a[2]; acc[oi][3] += c * a[3];
    }
  }
#pragma unroll 4
  for (int rs = 0; rs < 56; rs++) {
    const int rr = hi ? (rs ? (rs - 1) : 55) : rs;
    f32x4 a = *(const f32x4*)(A0 + (size_t)rr * 2048 + dd);
    const float* cr = &coef[(rs + 8) * 16];
#pragma unroll
    for (int oi = 0; oi < 16; oi++) {
      const float c = cr[oi];
      acc[oi][0] += c * a[0]; acc[oi][1] += c * a[1];
      acc[oi][2] += c * a[2]; acc[oi][3] += c * a[3];
    }
  }

#pragma unroll
  for (int oi = 0; oi < 16; oi++) {
    f32x4 w = *(const f32x4*)(W + (size_t)(o0 + oi) * 4096 + d0);
    ushort4 ov;
    ov.x = f2b(acc[oi][0] + w[0]);
    ov.y = f2b(acc[oi][1] + w[1]);
    ov.z = f2b(acc[oi][2] + w[2]);
    ov.w = f2b(acc[oi][3] + w[3]);
    *(ushort4*)(Weff + (size_t)(o0 + oi) * 4096 + d0) = ov;
  }
}

// ---------------------------------------------------------------------------
// Kernel 2: C[m][n] = sum_k Xb[m][k]*Weff[n][k] + bias[n]   (bf16 MFMA, NT)
//
// R5 structure (proven 242 us, 51% MfmaUtil) + T19 sched_group_barrier
// weave. R5 PMC arithmetic: per segment per CU, MFMA pipe 621 cyc + LDS
// unit 512 cyc = 1133 ~= measured 1134 -> the two ran SERIALLY. The weave
// pins the emitted order to {gloads; 1-2 ds_read per 4 MFMA} so the LDS
// queue drains UNDER the MFMA burst. No sync-structure change: barriers,
// VMWs, and memory ops are identical to R5 (race-free by construction).
//
//   S1: stage b(T+1)x4;   read B1(T);   MFMA(0,0); VMW(6) [drains r13(T)]
//   S2: stage r13(T+1);   read A1(T);   MFMA(0,1); VMW(6) [drains r02(T+1)]
//   S3: stage r02(T+2);   read A0(T+1); MFMA(1,0); VMW(4) [drains b(T+1)]
//   S4:                   read B0(T+1); MFMA(1,1)
// Ledger identical to R5 (verified passing). setprio now wraps the whole
// woven segment (so it cannot fence the weave).
// ---------------------------------------------------------------------------
__global__ __launch_bounds__(512, 2) void gemm_bt_bias(
    const u16* __restrict__ X, const u16* __restrict__ Wf,
    const float* __restrict__ bias, float* __restrict__ C) {
  __shared__ __align__(16) u16 lds[65536];  // 128 KiB

  const int tid = threadIdx.x;
  const int wave = tid >> 6;
  const int lane = tid & 63;
  const int wm = wave >> 2;    // 0..1
  const int wn = wave & 3;     // 0..3
  const int quad = lane >> 4;  // 0..3
  const int l16 = lane & 15;

  // T1: XCD-aware swizzle (512 blocks, 64 per XCD, n-fastest).
  const int wgid = ((blockIdx.x & 7) << 6) | (blockIdx.x >> 3);
  const int n0 = (wgid & 15) * BN;  // 16 n-tiles
  const int m0 = (wgid >> 4) * BM;  // 32 m-tiles

  // Staging: linear LDS dest (wave-uniform base + lane*16); global source
  // carries the inverse T2 swizzle: colblock = (l&7)^(l>>3).
  const int srow = lane >> 3;           // 0..7
  const int sq = lane & 7;
  const int scol = ((sq ^ srow) << 3);
  const u16* xg = X + (size_t)(m0 + wave * 8 + srow) * K_DIM + scol;
  const u16* wg = Wf + (size_t)(n0 + wave * 8 + srow) * K_DIM + scol;
  u16* lA = lds + wave * 512;           // wave-uniform
  u16* lB = lds + 32768 + wave * 512;

#define SG_A(b, r, kt)                                                      \
  GLOAD_LDS16(xg + (size_t)(r) * 64 * K_DIM + (size_t)(kt) * BK,            \
              lA + (b) * 16384 + (r) * 4096)
#define SG_B(b, r, kt)                                                      \
  GLOAD_LDS16(wg + (size_t)(r) * 64 * K_DIM + (size_t)(kt) * BK,            \
              lB + (b) * 16384 + (r) * 4096)

  f32x4 acc[8][4] = {};
  bf16x8 afr0[4][2];  // A0-half frags (mi, k)
  bf16x8 afr1[4][2];  // A1-half frags
  bf16x8 bfr0[2][2];  // B0-half frags (ni, k)
  bf16x8 bfr1[2][2];  // B1-half frags

  // T2 read swizzle: phys = (cb*16) ^ ((row&7)<<4); row&7 == l16&7 always.
  const int c0 = (quad << 4) ^ ((l16 & 7) << 4);

#define READ_A(dst, mh, ABASE)                                              \
  do {                                                                      \
    const char* ab_ =                                                       \
        (ABASE) + (size_t)((wm * 128 + (mh) * 64 + l16) * 128);             \
    _Pragma("unroll") for (int mi = 0; mi < 4; mi++) {                      \
      dst[mi][0] = *(const bf16x8*)(ab_ + mi * 2048 + c0);                  \
      dst[mi][1] = *(const bf16x8*)(ab_ + mi * 2048 + (c0 ^ 64));           \
    }                                                                       \
  } while (0)

#define READ_B(dst, nh, BBASE)                                              \
  do {                                                                      \
    const char* bb_ =                                                       \
        (BBASE) + (size_t)((wn * 64 + (nh) * 32 + l16) * 128);              \
    _Pragma("unroll") for (int ni = 0; ni < 2; ni++) {                      \
      dst[ni][0] = *(const bf16x8*)(bb_ + ni * 2048 + c0);                  \
      dst[ni][1] = *(const bf16x8*)(bb_ + ni * 2048 + (c0 ^ 64));           \
    }                                                                       \
  } while (0)

#define MFMA_Q(mh, nh, AF, BF)                                              \
  do {                                                                      \
    _Pragma("unroll") for (int mi = 0; mi < 4; mi++) {                      \
      _Pragma("unroll") for (int ni = 0; ni < 2; ni++) {                    \
        acc[(mh)*4 + mi][(nh)*2 + ni] =                                     \
            __builtin_amdgcn_mfma_f32_16x16x32_bf16(                        \
                AF[mi][0], BF[ni][0],                                       \
                acc[(mh)*4 + mi][(nh)*2 + ni], 0, 0, 0);                    \
        acc[(mh)*4 + mi][(nh)*2 + ni] =                                     \
            __builtin_amdgcn_mfma_f32_16x16x32_bf16(                        \
                AF[mi][1], BF[ni][1],                                       \
                acc[(mh)*4 + mi][(nh)*2 + ni], 0, 0, 0);                    \
      }                                                                     \
    }                                                                       \
  } while (0)

  // Prologue: b(0), r02(0), r13(0), r02(1) [10 DMA]. VMW(4) leaves
  // [r13(0), r02(1)] (steady-state entry); b(0)+r02(0) landed ->
  // pre-read A0(0), B0(0).
  SG_B(0, 0, 0); SG_B(0, 1, 0); SG_B(0, 2, 0); SG_B(0, 3, 0);
  SG_A(0, 0, 0); SG_A(0, 2, 0);
  SG_A(0, 1, 0); SG_A(0, 3, 0);
  SG_A(1, 0, 1); SG_A(1, 2, 1);
  VMW(4);
  BAR;
  READ_A(afr0, 0, (const char*)lds);
  READ_B(bfr0, 0, (const char*)lds + 65536);

  for (int T = 0; T < NT; ++T) {
    const int buf = T & 1;
    const int b1 = buf ^ 1;
    const char* Ab = (const char*)lds + buf * 32768;
    const char* AbN = (const char*)lds + b1 * 32768;
    const char* Bb = (const char*)lds + 65536 + buf * 32768;
    const char* BbN = (const char*)lds + 65536 + b1 * 32768;
    const int k1 = (T + 1 < NT) ? T + 1 : NT - 1;
    const int k2 = (T + 2 < NT) ? T + 2 : NT - 1;

    // S1: stage b(T+1); read B1(T); MFMA(0,0); drain r13(T).
    __builtin_amdgcn_s_setprio(1);
    SGB(0x70, 4);
    WEAVE_4R;
    SG_B(b1, 0, k1); SG_B(b1, 1, k1); SG_B(b1, 2, k1); SG_B(b1, 3, k1);
    READ_B(bfr1, 1, Bb);
    MFMA_Q(0, 0, afr0, bfr0);
    __builtin_amdgcn_s_setprio(0);
    VMW(6);
    BAR;

    // S2: stage r13(T+1); read A1(T); MFMA(0,1); drain r02(T+1).
    __builtin_amdgcn_s_setprio(1);
    SGB(0x70, 2);
    WEAVE_8R;
    SG_A(b1, 1, k1); SG_A(b1, 3, k1);
    READ_A(afr1, 1, Ab);
    MFMA_Q(0, 1, afr0, bfr1);
    __builtin_amdgcn_s_setprio(0);
    VMW(6);
    BAR;

    // S3: stage r02(T+2); read A0(T+1); MFMA(1,0); drain b(T+1).
    __builtin_amdgcn_s_setprio(1);
    SGB(0x70, 2);
    WEAVE_8R;
    SG_A(buf, 0, k2); SG_A(buf, 2, k2);
    READ_A(afr0, 0, AbN);
    MFMA_Q(1, 0, afr1, bfr0);
    __builtin_amdgcn_s_setprio(0);
    VMW(4);
    BAR;

    // S4: read B0(T+1); MFMA(1,1).
    __builtin_amdgcn_s_setprio(1);
    WEAVE_4R;
    READ_B(bfr0, 0, BbN);
    MFMA_Q(1, 1, afr1, bfr1);
    __builtin_amdgcn_s_setprio(0);
    BAR;
  }
  VMW(0);  // drain DMA before LDS goes out of scope

  // Epilogue: C/D layout col=l16 (B-frag j), row=quad*4+reg (A-frag i).
#pragma unroll
  for (int j = 0; j < 4; j++) {
    const int col = n0 + wn * 64 + j * 16 + l16;
    const float bv = bias[col];
#pragma unroll
    for (int i = 0; i < 8; i++) {
      const int row = m0 + wm * 128 + i * 16 + quad * 4;
#pragma unroll
      for (int r = 0; r < 4; r++) {
        C[(size_t)(row + r) * N_DIM + col] = acc[i][j][r] + bv;
      }
    }
  }
}

extern "C" void kernel_launch(void* const* d_in, const int* in_sizes, int n_in,
                              void* d_out, int out_size, void* d_ws, size_t ws_size,
                              hipStream_t stream) {
  const float* x  = (const float*)d_in[0];  // [4,2048,4096] fp32
  const float* W  = (const float*)d_in[1];  // [4096,4096] fp32
  const float* b  = (const float*)d_in[2];  // [4096] fp32
  const float* Au = (const float*)d_in[3];  // [8,4096] fp32
  const float* Bu = (const float*)d_in[4];  // [4096,8] fp32
  const float* A0 = (const float*)d_in[5];  // [56,2048] fp32
  const float* B0 = (const float*)d_in[6];  // [2048,56] fp32
  float* out = (float*)d_out;               // [4,2048,4096] fp32

  u16* Xb   = (u16*)d_ws;                                      // 64 MB
  u16* Weff = (u16*)((char*)d_ws + (size_t)64 * 1024 * 1024);  // 32 MB

  cvt_x<<<16384, 256, 0, stream>>>(x, Xb);
  build_weff<<<dim3(4, 256), 256, 0, stream>>>(W, Au, Bu, A0, B0, Weff);
  gemm_bt_bias<<<dim3(512), dim3(512), 0, stream>>>(Xb, Weff, b, out);
}